// Round 9
// baseline (426.031 us; speedup 1.0000x reference)
//
#include <hip/hip_runtime.h>
#include <math.h>

typedef unsigned long long ull;
typedef unsigned int uint;

#define NBOX 21840
#define SEGSZ 512
#define NSEG 44
#define NPAD (NSEG*SEGSZ)     // 22528
#define PFXS 23               // staged (key+box) per segment
#define OUTW 24               // 23 staged + 1 pref key
#define NWALK (NSEG*PFXS)     // 1012
#define MCAP 1024
#define WIN 512               // fast window with precomputed within-batch masks
#define BATCH 32
#define NCLS 21
#define NEGV -1e30f
// midpoint(0.45f, nextafterf(0.45f)) = 15099494.5 * 2^-25, exactly representable.
// RN(inter/u) > 0.45f  <=>  (double)inter > MIOU * (double)u   (u > 0)
#define MIOU (15099494.5/33554432.0)

// ---- sortable key: ascending u64 == (score desc, idx asc) ----
// lo = (idx<<16) | (slot<<5) | cls   (slot/cls below idx: never affect (score,idx) order)
__device__ __forceinline__ uint key_hi(float s) {
    uint b = __float_as_uint(s);
    uint m = (uint)((int)b >> 31) | 0x80000000u;
    return ~(b ^ m);                       // valid (s>0.01>0) => hi < 0x80000000
}
__device__ __forceinline__ float key_score(uint hi) {
    uint srt = ~hi;
    uint b = (srt & 0x80000000u) ? (srt ^ 0x80000000u) : ~srt;
    return __uint_as_float(b);
}

__device__ __forceinline__ float area_of(float4 b) {
    return __fmul_rn(__fsub_rn(b.z, b.x), __fsub_rn(b.w, b.y));
}
// exact iou>0.45 decision, divide-free (strict > at midpoint; tie rounds to even=0.45f)
__device__ __forceinline__ bool sup_check(float4 a, float aarea, float4 c, float carea) {
    float ix1 = fmaxf(a.x, c.x), iy1 = fmaxf(a.y, c.y);
    float ix2 = fminf(a.z, c.z), iy2 = fminf(a.w, c.w);
    float inter = __fmul_rn(fmaxf(__fsub_rn(ix2, ix1), 0.f), fmaxf(__fsub_rn(iy2, iy1), 0.f));
    float uni = __fsub_rn(__fadd_rn(aarea, carea), inter);
    return (uni > 0.f) && ((double)inter > MIOU * (double)fmaxf(uni, 1e-12f));
}

__device__ __forceinline__ float4 decode_box(float t0, float t1, float t2, float t3, float4 a) {
    float cx = __fadd_rn(__fmul_rn(__fmul_rn(t0, 0.1f), a.z), a.x);
    float cy = __fadd_rn(__fmul_rn(__fmul_rn(t1, 0.1f), a.w), a.y);
    float w  = __fmul_rn((float)exp((double)__fmul_rn(t2, 0.2f)), a.z);
    float h  = __fmul_rn((float)exp((double)__fmul_rn(t3, 0.2f)), a.w);
    float hw = __fmul_rn(0.5f, w), hh = __fmul_rn(0.5f, h);
    return make_float4(fminf(fmaxf(__fsub_rn(cx, hw), 0.f), 1.f),
                       fminf(fmaxf(__fsub_rn(cy, hh), 0.f), 1.f),
                       fminf(fmaxf(__fadd_rn(cx, hw), 0.f), 1.f),
                       fminf(fmaxf(__fadd_rn(cy, hh), 0.f), 1.f));
}

// one bitonic compare-exchange pass with j<=32: partner is in-wave, via shfl
__device__ __forceinline__ ull cex_shfl(ull v, int j, bool asc, int lane) {
    ull pv = __shfl_xor(v, j);
    bool keepmin = (((lane & j) == 0) == asc);
    bool less = (v < pv);
    return (keepmin == less) ? v : pv;
}

// ---------------- fused decode + top-24 + tail-block NMS ----------------
__global__ __launch_bounds__(512, 6) void fused_kernel(
    const float* __restrict__ y_pred, const float* __restrict__ box_tensor,
    ull* __restrict__ KS, ull* __restrict__ K2, float4* __restrict__ SBX,
    int* __restrict__ ctr, float* __restrict__ out)
{
    __shared__ union {
        struct { float st[SEGSZ * 25]; ull mbuf[8 * 24]; } d;                  // 52.7 KB
        struct { ull klist[MCAP]; float4 cbox[WIN]; ull scol[WIN];
                 float4 accbox[100]; float accarea[100]; ull pref[NSEG]; } n;  // 22.8 KB
    } sh;
    __shared__ int flag;

    int img = blockIdx.y, seg = blockIdx.x, tid = threadIdx.x;
    int wid = tid >> 6, lane = tid & 63;
    int b0 = seg * SEGSZ;

    // ---------------- decode phase ----------------
    int nval = NBOX - b0; nval = nval < 0 ? 0 : (nval > SEGSZ ? SEGSZ : nval);
    if (nval > 0) {
        const float* src = y_pred + ((size_t)img * NBOX + b0) * 25;
        int nf = nval * 25, nf4 = nf >> 2;
        const float4* src4 = (const float4*)src;
        float4* st4 = (float4*)sh.d.st;
        for (int f = tid; f < nf4; f += 512) st4[f] = src4[f];
        for (int f = (nf4 << 2) + tid; f < nf; f += 512) sh.d.st[f] = src[f];
    }
    __syncthreads();
    int i = b0 + tid;
    ull v;
    if (tid < nval) {
        const float* yl = sh.d.st + tid * 25;
        float best = yl[0]; int bi = 0;
        #pragma unroll
        for (int k = 1; k < NCLS; k++) { float x = yl[k]; if (x > best) { best = x; bi = k; } }
        float4 a = ((const float4*)box_tensor)[i];
        bool valid = (bi != 0) && (best > 0.01f);
        uint hi = valid ? key_hi(best) : __float_as_uint(NEGV);
        v = ((ull)hi << 32) | ((uint)(i << 16)) | (uint)bi;
    } else {
        v = ((ull)__float_as_uint(NEGV) << 32) | ((uint)(i << 16));
    }
    KS[(size_t)img * NPAD + b0 + tid] = v;     // raw keys (slot=0): phase-C fallback only

    // wave-local full sort of 64 keys (shfl-only, zero barriers)
    for (int k = 2; k <= 64; k <<= 1) {
        bool asc = (k == 64) || ((lane & k) == 0);
        for (int j = k >> 1; j >= 1; j >>= 1)
            v = cex_shfl(v, j, asc, lane);
    }
    if (lane < 24) sh.d.mbuf[wid * 24 + lane] = v;
    __syncthreads();

    if (wid == 0) {
        // wave 0: in-register 256-sort of the 192 wave-top-24s, emit top-24 + staged boxes
        ull m[4];
        #pragma unroll
        for (int r = 0; r < 4; r++) {
            int e = (r << 6) + lane;
            m[r] = (e < 192) ? sh.d.mbuf[e] : ~0ull;
        }
        for (int k = 2; k <= 256; k <<= 1) {
            #pragma unroll
            for (int jr = 2; jr >= 1; jr >>= 1) {      // j = 128, 64: same-lane register CE
                int j = jr << 6;
                if ((k >> 1) >= j) {
                    #pragma unroll
                    for (int r = 0; r < 4; r++) {
                        if ((r & jr) == 0) {
                            int rh = r | jr;
                            int e = (r << 6) + lane;
                            bool asc = ((e & k) == 0) || (k == 256);
                            ull a = m[r], b = m[rh];
                            if ((a > b) == asc) { m[r] = b; m[rh] = a; }
                        }
                    }
                }
            }
            int j0 = (k >> 1) < 32 ? (k >> 1) : 32;
            for (int j = j0; j >= 1; j >>= 1) {
                #pragma unroll
                for (int r = 0; r < 4; r++) {
                    int e = (r << 6) + lane;
                    bool asc = ((e & k) == 0) || (k == 256);
                    m[r] = cex_shfl(m[r], j, asc, lane);
                }
            }
        }
        ull m0 = m[0];
        size_t krow = (size_t)img * (NSEG * OUTW) + seg * OUTW;
        if (lane < PFXS) {
            int slot = seg * PFXS + lane;
            K2[krow + lane] = m0 | ((ull)(slot << 5));
            float4 bx = make_float4(9.f, 9.f, 9.f, 9.f);
            if (!(m0 >> 63)) {
                uint idx = (uint)((m0 >> 16) & 0x7FFFull);
                int loc = (int)idx - b0;
                const float* yl = sh.d.st + loc * 25;
                float4 a = ((const float4*)box_tensor)[idx];
                bx = decode_box(yl[21], yl[22], yl[23], yl[24], a);
            }
            SBX[(size_t)img * NWALK + slot] = bx;
        } else if (lane == PFXS) {
            K2[krow + PFXS] = m0;              // pref key, raw (slot bits 0)
        }
    }

    // ---------------- tail-block election (device-scope) ----------------
    __threadfence();
    __syncthreads();
    if (tid == 0) {
        int old = atomicAdd(&ctr[img], 1);
        flag = (old == NSEG - 1);
    }
    __syncthreads();
    if (!flag) return;
    __threadfence();                           // acquire: other blocks' K2/SBX/KS writes

    // ---------------- NMS phase (one block per image) ----------------
    const ull* k2i = K2 + (size_t)img * (NSEG * OUTW);
    const float4* SBXg = SBX + (size_t)img * NWALK;

    ull v2[2];
    #pragma unroll
    for (int r = 0; r < 2; r++) {
        int e = (wid << 7) + (r << 6) + lane;
        v2[r] = (e < NWALK) ? k2i[(e / PFXS) * OUTW + (e % PFXS)] : ~0ull;
    }
    ull prefv = (tid < NSEG) ? k2i[tid * OUTW + PFXS] : ~0ull;
    __syncthreads();                           // LDS overlay boundary (st -> n)
    if (tid < NSEG) sh.n.pref[tid] = prefv;

    // hybrid bitonic sort 1024 ascending: LDS (j>=128), reg (j=64), shfl (j<=32)
    for (int k = 2; k <= MCAP; k <<= 1) {
        if ((k >> 1) >= 128) {
            #pragma unroll
            for (int r = 0; r < 2; r++) sh.n.klist[(wid << 7) + (r << 6) + lane] = v2[r];
            for (int j = k >> 1; j >= 128; j >>= 1) {
                __syncthreads();
                int t = tid;
                int ii = ((t & ~(j - 1)) << 1) | (t & (j - 1));
                int l = ii | j;
                ull a = sh.n.klist[ii], b = sh.n.klist[l];
                if ((a > b) == ((ii & k) == 0)) { sh.n.klist[ii] = b; sh.n.klist[l] = a; }
            }
            __syncthreads();
            #pragma unroll
            for (int r = 0; r < 2; r++) v2[r] = sh.n.klist[(wid << 7) + (r << 6) + lane];
        }
        if ((k >> 1) >= 64) {                  // j = 64: same-lane register CE
            int e = (wid << 7) + lane;
            bool asc = ((e & k) == 0);
            ull a = v2[0], b = v2[1];
            if ((a > b) == asc) { v2[0] = b; v2[1] = a; }
        }
        int j0 = (k >> 1) < 32 ? (k >> 1) : 32;
        for (int j = j0; j >= 1; j >>= 1) {
            #pragma unroll
            for (int r = 0; r < 2; r++) {
                int e = (wid << 7) + (r << 6) + lane;
                v2[r] = cex_shfl(v2[r], j, (e & k) == 0, lane);
            }
        }
    }
    #pragma unroll
    for (int r = 0; r < 2; r++) sh.n.klist[(wid << 7) + (r << 6) + lane] = v2[r];
    __syncthreads();

    // window prep: wave w handles batch w (boxes from contiguous staged array via slot bits)
    {
        int c = (wid << 6) + lane;
        ull k = sh.n.klist[c];
        float4 bx = make_float4(9.f, 9.f, 9.f, 9.f);
        if (!(k >> 63)) bx = SBXg[(uint)((k >> 5) & 0x7FFull)];
        sh.n.cbox[c] = bx;
        float myar = area_of(bx);
        ull col = 0;
        #pragma unroll 4
        for (int q = 0; q < 64; q++) {
            float4 ib = sh.n.cbox[(wid << 6) + q];
            bool s = (q < lane) && sup_check(ib, area_of(ib), bx, myar);
            col |= ((ull)s) << q;
        }
        sh.n.scol[c] = col;
    }
    __syncthreads();

    if (tid >= 64) return;             // resolve: wave 0 only
    float* orow = out + (size_t)img * 600;
    const ull* ksg = KS + (size_t)img * NPAD;

    ull cutk = ~0ull;
    for (int s = 0; s < NSEG; s++) { ull x = sh.n.pref[s]; if (x < cutk) cutk = x; }

    int A = 0, stop = 0, done = 0;
    int acc0 = 0, acc1 = 0;            // accepted window positions per lane

    for (int base = 0; base < WIN && !stop; base += 64) {
        int c = base + lane;
        ull kk = sh.n.klist[c];
        float4 bb = sh.n.cbox[c];
        float ca = area_of(bb);
        ull mycol = sh.n.scol[c];
        bool valid = !(kk >> 63) && (kk < cutk);
        ull vmask = __ballot(valid);
        bool alive = valid;
        for (int a = 0; a < A; a++)
            alive = alive & !sup_check(sh.n.accbox[a], sh.n.accarea[a], bb, ca);
        ull m = __ballot(alive);
        while (m && A < 100) {
            int q = __ffsll(m) - 1;
            if (lane == q) { sh.n.accbox[A] = bb; sh.n.accarea[A] = ca; }
            if (lane == (A & 63)) { if (A < 64) acc0 = base + q; else acc1 = base + q; }
            A++;
            m &= ~(1ull << q);
            m &= __ballot(!((mycol >> q) & 1ull));
        }
        if (A >= 100) { stop = 1; done = 1; }
        else if (vmask != ~0ull) {
            stop = 1;
            int fi = __ffsll(~vmask) - 1;
            ull fk = __shfl(kk, fi);
            done = (fk >= cutk) ? (int)(cutk >> 63) : 1;
        }
        __builtin_amdgcn_wave_barrier();
    }

    // batch-write window outputs (lane-parallel)
    int accW = A;
    if (lane < accW) {
        ull k = sh.n.klist[acc0]; float4 b = sh.n.cbox[acc0];
        float* o = orow + lane * 6;
        o[0] = (float)((uint)k & 0x1Fu); o[1] = key_score((uint)(k >> 32));
        o[2] = b.x; o[3] = b.y; o[4] = b.z; o[5] = b.w;
    }
    if (64 + lane < accW) {
        ull k = sh.n.klist[acc1]; float4 b = sh.n.cbox[acc1];
        float* o = orow + (64 + lane) * 6;
        o[0] = (float)((uint)k & 0x1Fu); o[1] = key_score((uint)(k >> 32));
        o[2] = b.x; o[3] = b.y; o[4] = b.z; o[5] = b.w;
    }

    // phase B: staged keys beyond the window (expected dead: walk depth ~200 < WIN)
    if (!stop) {
        for (int base = WIN; base < MCAP && !stop; base += 64) {
            int pos = base + lane;
            ull kk = sh.n.klist[pos];
            bool valid = !(kk >> 63) && (kk < cutk);
            ull vmask = __ballot(valid);
            float4 bb = make_float4(9.f, 9.f, 9.f, 9.f);
            if (!(kk >> 63)) bb = SBXg[(uint)((kk >> 5) & 0x7FFull)];
            float ca = area_of(bb);
            bool alive = valid;
            for (int a = 0; a < A; a++)
                alive = alive & !sup_check(sh.n.accbox[a], sh.n.accarea[a], bb, ca);
            ull cand = __ballot(alive);
            while (cand && A < 100) {
                int q = __ffsll(cand) - 1;
                float4 ib = make_float4(__shfl(bb.x, q), __shfl(bb.y, q),
                                        __shfl(bb.z, q), __shfl(bb.w, q));
                float ia = __shfl(ca, q);
                ull row = __ballot(sup_check(ib, ia, bb, ca));
                if (lane == q) {
                    sh.n.accbox[A] = bb; sh.n.accarea[A] = ca;
                    float* o = orow + A * 6;
                    o[0] = (float)((uint)kk & 0x1Fu); o[1] = key_score((uint)(kk >> 32));
                    o[2] = bb.x; o[3] = bb.y; o[4] = bb.z; o[5] = bb.w;
                }
                A++;
                cand &= ~(1ull << q);
                cand &= ~row;
            }
            if (A >= 100) { stop = 1; done = 1; }
            else if (vmask != ~0ull) {
                stop = 1;
                int fi = __ffsll(~vmask) - 1;
                ull fk = __shfl(kk, fi);
                done = (fk >= cutk) ? (int)(cutk >> 63) : 1;
            }
            __builtin_amdgcn_wave_barrier();
        }
        if (!stop) done = (int)(cutk >> 63);
    }

    // phase C fallback (expected dead): ordered pops over full raw key array from cutk;
    // box recomputed bit-exactly from y_pred + box_tensor
    if (!done && A < 100) {
        ull nextk = cutk;                       // cutk has slot bits 0, comparable with KS keys
        while (A < 100) {
            ull best = ~0ull;
            for (int e = lane; e < NPAD; e += 64) {
                ull kk2 = ksg[e];
                if (kk2 >= nextk && kk2 < best) best = kk2;
            }
            #pragma unroll
            for (int off = 32; off; off >>= 1) {
                ull oo = __shfl_xor(best, off);
                if (oo < best) best = oo;
            }
            if (best >> 63) break;
            uint bhi = (uint)(best >> 32);
            uint idx = (uint)((best >> 16) & 0x7FFFull);
            float4 a = ((const float4*)box_tensor)[idx];
            const float* yp = y_pred + ((size_t)img * NBOX + idx) * 25;
            float4 cb = decode_box(yp[21], yp[22], yp[23], yp[24], a);
            float ca2 = area_of(cb);
            bool sup2 = false;
            #pragma unroll
            for (int t = 0; t < 2; t++) {
                int slot = lane + 64 * t;
                if (slot < A && sup_check(sh.n.accbox[slot], sh.n.accarea[slot], cb, ca2)) sup2 = true;
            }
            if (__ballot(sup2) == 0ull) {
                if (lane == 0) {
                    sh.n.accbox[A] = cb; sh.n.accarea[A] = ca2;
                    float* o = orow + A * 6;
                    o[0] = (float)((uint)best & 0x1Fu); o[1] = key_score(bhi);
                    o[2] = cb.x; o[3] = cb.y; o[4] = cb.z; o[5] = cb.w;
                }
                A++;
            }
            nextk = best + 1;
            __builtin_amdgcn_wave_barrier();
        }
    }

    for (int r = lane; r < (100 - A) * 6; r += 64) orow[A * 6 + r] = 0.f;
}

extern "C" void kernel_launch(void* const* d_in, const int* in_sizes, int n_in,
                              void* d_out, int out_size, void* d_ws, size_t ws_size,
                              hipStream_t stream)
{
    const float* y_pred     = (const float*)d_in[0];
    const float* box_tensor = (const float*)d_in[1];
    float* out = (float*)d_out;

    int* ctr = (int*)d_ws;                                      // 32 counters (zeroed below)
    ull* KS  = (ull*)((char*)d_ws + 256);                       // 5.77 MB raw keys
    ull* K2  = KS + (size_t)BATCH * NPAD;                       // 0.27 MB staged keys
    float4* SBX = (float4*)(K2 + (size_t)BATCH * NSEG * OUTW);  // 0.52 MB staged boxes

    hipMemsetAsync(ctr, 0, 256, stream);
    fused_kernel<<<dim3(NSEG, BATCH), 512, 0, stream>>>(
        y_pred, box_tensor, KS, K2, SBX, ctr, out);
}

// Round 10
// 137.809 us; speedup vs baseline: 3.0915x; 3.0915x over previous
//
#include <hip/hip_runtime.h>
#include <math.h>

typedef unsigned long long ull;
typedef unsigned int uint;

#define NBOX 21840
#define SEGSZ 512
#define NSEG 44
#define NPAD (NSEG*SEGSZ)     // 22528
#define PFXS 23               // staged (key+box) per segment
#define OUTW 24               // 23 staged + 1 pref key
#define NWALK (NSEG*PFXS)     // 1012
#define MCAP 1024
#define WIN 512               // fast window with precomputed within-batch masks
#define BATCH 32
#define NCLS 21
#define NEGV -1e30f
// midpoint(0.45f, nextafterf(0.45f)) = 15099494.5 * 2^-25, exactly representable.
// RN(inter/u) > 0.45f  <=>  (double)inter > MIOU * (double)u   (u > 0)
#define MIOU (15099494.5/33554432.0)

// ---- sortable key: ascending u64 == (score desc, idx asc) ----
// lo = (idx<<16) | (slot<<5) | cls   (slot/cls below idx: never affect (score,idx) order)
__device__ __forceinline__ uint key_hi(float s) {
    uint b = __float_as_uint(s);
    uint m = (uint)((int)b >> 31) | 0x80000000u;
    return ~(b ^ m);                       // valid (s>0.01>0) => hi < 0x80000000
}
__device__ __forceinline__ float key_score(uint hi) {
    uint srt = ~hi;
    uint b = (srt & 0x80000000u) ? (srt ^ 0x80000000u) : ~srt;
    return __uint_as_float(b);
}

__device__ __forceinline__ float area_of(float4 b) {
    return __fmul_rn(__fsub_rn(b.z, b.x), __fsub_rn(b.w, b.y));
}
// exact iou>0.45 decision, divide-free (strict > at midpoint; tie rounds to even=0.45f)
__device__ __forceinline__ bool sup_check(float4 a, float aarea, float4 c, float carea) {
    float ix1 = fmaxf(a.x, c.x), iy1 = fmaxf(a.y, c.y);
    float ix2 = fminf(a.z, c.z), iy2 = fminf(a.w, c.w);
    float inter = __fmul_rn(fmaxf(__fsub_rn(ix2, ix1), 0.f), fmaxf(__fsub_rn(iy2, iy1), 0.f));
    float uni = __fsub_rn(__fadd_rn(aarea, carea), inter);
    return (uni > 0.f) && ((double)inter > MIOU * (double)fmaxf(uni, 1e-12f));
}

__device__ __forceinline__ float4 decode_box(float t0, float t1, float t2, float t3, float4 a) {
    float cx = __fadd_rn(__fmul_rn(__fmul_rn(t0, 0.1f), a.z), a.x);
    float cy = __fadd_rn(__fmul_rn(__fmul_rn(t1, 0.1f), a.w), a.y);
    float w  = __fmul_rn((float)exp((double)__fmul_rn(t2, 0.2f)), a.z);
    float h  = __fmul_rn((float)exp((double)__fmul_rn(t3, 0.2f)), a.w);
    float hw = __fmul_rn(0.5f, w), hh = __fmul_rn(0.5f, h);
    return make_float4(fminf(fmaxf(__fsub_rn(cx, hw), 0.f), 1.f),
                       fminf(fmaxf(__fsub_rn(cy, hh), 0.f), 1.f),
                       fminf(fmaxf(__fadd_rn(cx, hw), 0.f), 1.f),
                       fminf(fmaxf(__fadd_rn(cy, hh), 0.f), 1.f));
}

// one bitonic compare-exchange pass with j<=32: partner is in-wave, via shfl
__device__ __forceinline__ ull cex_shfl(ull v, int j, bool asc, int lane) {
    ull pv = __shfl_xor(v, j);
    bool keepmin = (((lane & j) == 0) == asc);
    bool less = (v < pv);
    return (keepmin == less) ? v : pv;
}

// ---------------- Kernel A: decode + hierarchical top-24; emit compact keys+boxes only ----------------
__global__ __launch_bounds__(512) void decode_sort_kernel(
    const float* __restrict__ y_pred, const float* __restrict__ box_tensor,
    ull* __restrict__ K2, float4* __restrict__ SBX)
{
    __shared__ float st[SEGSZ * 25];   // 51.2 KB
    __shared__ ull mbuf[8 * 24];       // 1.5 KB: per-wave top-24
    int img = blockIdx.y, seg = blockIdx.x, tid = threadIdx.x;
    int wid = tid >> 6, lane = tid & 63;
    int b0 = seg * SEGSZ;
    int nval = NBOX - b0; nval = nval < 0 ? 0 : (nval > SEGSZ ? SEGSZ : nval);
    if (nval > 0) {
        const float* src = y_pred + ((size_t)img * NBOX + b0) * 25;
        int nf = nval * 25, nf4 = nf >> 2;
        const float4* src4 = (const float4*)src;
        float4* st4 = (float4*)st;
        for (int f = tid; f < nf4; f += 512) st4[f] = src4[f];
        for (int f = (nf4 << 2) + tid; f < nf; f += 512) st[f] = src[f];
    }
    __syncthreads();
    int i = b0 + tid;
    ull v;
    if (tid < nval) {
        const float* yl = st + tid * 25;
        float best = yl[0]; int bi = 0;
        #pragma unroll
        for (int k = 1; k < NCLS; k++) { float x = yl[k]; if (x > best) { best = x; bi = k; } }
        bool valid = (bi != 0) && (best > 0.01f);
        uint hi = valid ? key_hi(best) : __float_as_uint(NEGV);
        v = ((ull)hi << 32) | ((uint)(i << 16)) | (uint)bi;
    } else {
        v = ((ull)__float_as_uint(NEGV) << 32) | ((uint)(i << 16));
    }

    // wave-local full sort of 64 keys (shfl-only, zero barriers)
    for (int k = 2; k <= 64; k <<= 1) {
        bool asc = (k == 64) || ((lane & k) == 0);
        for (int j = k >> 1; j >= 1; j >>= 1)
            v = cex_shfl(v, j, asc, lane);
    }
    if (lane < 24) mbuf[wid * 24 + lane] = v;
    __syncthreads();

    if (wid != 0) return;

    // wave 0: in-register 256-sort of the 192 wave-top-24s, emit top-24 + staged boxes
    ull m[4];
    #pragma unroll
    for (int r = 0; r < 4; r++) {
        int e = (r << 6) + lane;
        m[r] = (e < 192) ? mbuf[e] : ~0ull;
    }
    for (int k = 2; k <= 256; k <<= 1) {
        #pragma unroll
        for (int jr = 2; jr >= 1; jr >>= 1) {      // j = 128, 64: same-lane register CE
            int j = jr << 6;
            if ((k >> 1) >= j) {
                #pragma unroll
                for (int r = 0; r < 4; r++) {
                    if ((r & jr) == 0) {
                        int rh = r | jr;
                        int e = (r << 6) + lane;
                        bool asc = ((e & k) == 0) || (k == 256);
                        ull a = m[r], b = m[rh];
                        if ((a > b) == asc) { m[r] = b; m[rh] = a; }
                    }
                }
            }
        }
        int j0 = (k >> 1) < 32 ? (k >> 1) : 32;
        for (int j = j0; j >= 1; j >>= 1) {
            #pragma unroll
            for (int r = 0; r < 4; r++) {
                int e = (r << 6) + lane;
                bool asc = ((e & k) == 0) || (k == 256);
                m[r] = cex_shfl(m[r], j, asc, lane);
            }
        }
    }
    ull m0 = m[0];
    size_t krow = (size_t)img * (NSEG * OUTW) + seg * OUTW;
    if (lane < PFXS) {
        int slot = seg * PFXS + lane;
        K2[krow + lane] = m0 | ((ull)(slot << 5));
        float4 bx = make_float4(9.f, 9.f, 9.f, 9.f);
        if (!(m0 >> 63)) {
            uint idx = (uint)((m0 >> 16) & 0x7FFFull);
            int loc = (int)idx - b0;
            const float* yl = st + loc * 25;
            float4 a = ((const float4*)box_tensor)[idx];
            bx = decode_box(yl[21], yl[22], yl[23], yl[24], a);
        }
        SBX[(size_t)img * NWALK + slot] = bx;
    } else if (lane == PFXS) {
        K2[krow + PFXS] = m0;              // pref key, raw (slot bits 0)
    }
}

// ---------------- Kernel B: merge + batched greedy walk w/ precomputed in-batch masks ----------------
__global__ __launch_bounds__(512) void nms_kernel(
    const ull* __restrict__ K2, const float4* __restrict__ SBX,
    const float* __restrict__ y_pred, const float* __restrict__ box_tensor,
    float* __restrict__ out)
{
    __shared__ ull klist[MCAP];        // 8 KB
    __shared__ float4 cbox[WIN];       // 8 KB
    __shared__ ull scol[WIN];          // 4 KB
    __shared__ float4 accbox[100];
    __shared__ float  accarea[100];
    __shared__ ull pref[NSEG];

    int img = blockIdx.x, tid = threadIdx.x;
    int wid = tid >> 6, lane = tid & 63;
    const ull* k2i = K2 + (size_t)img * (NSEG * OUTW);
    const float4* SBXg = SBX + (size_t)img * NWALK;

    // stage 44 sorted prefixes of 23 into registers; e = wid*128 + r*64 + lane
    ull v[2];
    #pragma unroll
    for (int r = 0; r < 2; r++) {
        int e = (wid << 7) + (r << 6) + lane;
        v[r] = (e < NWALK) ? k2i[(e / PFXS) * OUTW + (e % PFXS)] : ~0ull;
    }
    if (tid < NSEG) pref[tid] = k2i[tid * OUTW + PFXS];

    // hybrid bitonic sort 1024 ascending: LDS (j>=128), reg (j=64), shfl (j<=32)
    for (int k = 2; k <= MCAP; k <<= 1) {
        if ((k >> 1) >= 128) {
            #pragma unroll
            for (int r = 0; r < 2; r++) klist[(wid << 7) + (r << 6) + lane] = v[r];
            for (int j = k >> 1; j >= 128; j >>= 1) {
                __syncthreads();
                int t = tid;
                int ii = ((t & ~(j - 1)) << 1) | (t & (j - 1));
                int l = ii | j;
                ull a = klist[ii], b = klist[l];
                if ((a > b) == ((ii & k) == 0)) { klist[ii] = b; klist[l] = a; }
            }
            __syncthreads();
            #pragma unroll
            for (int r = 0; r < 2; r++) v[r] = klist[(wid << 7) + (r << 6) + lane];
        }
        if ((k >> 1) >= 64) {              // j = 64: same-lane register CE
            int e = (wid << 7) + lane;
            bool asc = ((e & k) == 0);
            ull a = v[0], b = v[1];
            if ((a > b) == asc) { v[0] = b; v[1] = a; }
        }
        int j0 = (k >> 1) < 32 ? (k >> 1) : 32;
        for (int j = j0; j >= 1; j >>= 1) {
            #pragma unroll
            for (int r = 0; r < 2; r++) {
                int e = (wid << 7) + (r << 6) + lane;
                v[r] = cex_shfl(v[r], j, (e & k) == 0, lane);
            }
        }
    }
    #pragma unroll
    for (int r = 0; r < 2; r++) klist[(wid << 7) + (r << 6) + lane] = v[r];
    __syncthreads();

    // window prep: wave w handles batch w (boxes from compact staged array via slot bits)
    {
        int c = (wid << 6) + lane;
        ull k = klist[c];
        float4 bx = make_float4(9.f, 9.f, 9.f, 9.f);
        if (!(k >> 63)) bx = SBXg[(uint)((k >> 5) & 0x7FFull)];
        cbox[c] = bx;
        float myar = area_of(bx);
        ull col = 0;
        #pragma unroll 4
        for (int q = 0; q < 64; q++) {
            float4 ib = cbox[(wid << 6) + q];
            bool s = (q < lane) && sup_check(ib, area_of(ib), bx, myar);
            col |= ((ull)s) << q;
        }
        scol[c] = col;
    }
    __syncthreads();

    if (tid >= 64) return;             // resolve: wave 0 only
    float* orow = out + (size_t)img * 600;

    ull cutk = ~0ull;
    for (int s = 0; s < NSEG; s++) { ull x = pref[s]; if (x < cutk) cutk = x; }

    int A = 0, stop = 0, done = 0;
    int acc0 = 0, acc1 = 0;            // accepted window positions per lane

    for (int base = 0; base < WIN && !stop; base += 64) {
        int c = base + lane;
        ull kk = klist[c];
        float4 bb = cbox[c];
        float ca = area_of(bb);
        ull mycol = scol[c];
        bool valid = !(kk >> 63) && (kk < cutk);
        ull vmask = __ballot(valid);
        bool alive = valid;
        for (int a = 0; a < A; a++)
            alive = alive & !sup_check(accbox[a], accarea[a], bb, ca);
        ull m = __ballot(alive);
        while (m && A < 100) {
            int q = __ffsll(m) - 1;
            if (lane == q) { accbox[A] = bb; accarea[A] = ca; }
            if (lane == (A & 63)) { if (A < 64) acc0 = base + q; else acc1 = base + q; }
            A++;
            m &= ~(1ull << q);
            m &= __ballot(!((mycol >> q) & 1ull));
        }
        if (A >= 100) { stop = 1; done = 1; }
        else if (vmask != ~0ull) {
            stop = 1;
            int fi = __ffsll(~vmask) - 1;
            ull fk = __shfl(kk, fi);
            done = (fk >= cutk) ? (int)(cutk >> 63) : 1;
        }
        __builtin_amdgcn_wave_barrier();
    }

    // batch-write window outputs (lane-parallel)
    int accW = A;
    if (lane < accW) {
        ull k = klist[acc0]; float4 b = cbox[acc0];
        float* o = orow + lane * 6;
        o[0] = (float)((uint)k & 0x1Fu); o[1] = key_score((uint)(k >> 32));
        o[2] = b.x; o[3] = b.y; o[4] = b.z; o[5] = b.w;
    }
    if (64 + lane < accW) {
        ull k = klist[acc1]; float4 b = cbox[acc1];
        float* o = orow + (64 + lane) * 6;
        o[0] = (float)((uint)k & 0x1Fu); o[1] = key_score((uint)(k >> 32));
        o[2] = b.x; o[3] = b.y; o[4] = b.z; o[5] = b.w;
    }

    // phase B: staged keys beyond the window (expected dead: walk depth ~200 < WIN)
    if (!stop) {
        for (int base = WIN; base < MCAP && !stop; base += 64) {
            int pos = base + lane;
            ull kk = klist[pos];
            bool valid = !(kk >> 63) && (kk < cutk);
            ull vmask = __ballot(valid);
            float4 bb = make_float4(9.f, 9.f, 9.f, 9.f);
            if (!(kk >> 63)) bb = SBXg[(uint)((kk >> 5) & 0x7FFull)];
            float ca = area_of(bb);
            bool alive = valid;
            for (int a = 0; a < A; a++)
                alive = alive & !sup_check(accbox[a], accarea[a], bb, ca);
            ull cand = __ballot(alive);
            while (cand && A < 100) {
                int q = __ffsll(cand) - 1;
                float4 ib = make_float4(__shfl(bb.x, q), __shfl(bb.y, q),
                                        __shfl(bb.z, q), __shfl(bb.w, q));
                float ia = __shfl(ca, q);
                ull row = __ballot(sup_check(ib, ia, bb, ca));
                if (lane == q) {
                    accbox[A] = bb; accarea[A] = ca;
                    float* o = orow + A * 6;
                    o[0] = (float)((uint)kk & 0x1Fu); o[1] = key_score((uint)(kk >> 32));
                    o[2] = bb.x; o[3] = bb.y; o[4] = bb.z; o[5] = bb.w;
                }
                A++;
                cand &= ~(1ull << q);
                cand &= ~row;
            }
            if (A >= 100) { stop = 1; done = 1; }
            else if (vmask != ~0ull) {
                stop = 1;
                int fi = __ffsll(~vmask) - 1;
                ull fk = __shfl(kk, fi);
                done = (fk >= cutk) ? (int)(cutk >> 63) : 1;
            }
            __builtin_amdgcn_wave_barrier();
        }
        if (!stop) done = (int)(cutk >> 63);
    }

    // phase C fallback (expected dead): ordered pops recomputing keys/boxes from y_pred
    if (!done && A < 100) {
        ull nextk = cutk;
        while (A < 100) {
            ull best = ~0ull;
            for (int e = lane; e < NBOX; e += 64) {
                const float* yp = y_pred + ((size_t)img * NBOX + e) * 25;
                float bs = yp[0]; int bi = 0;
                #pragma unroll
                for (int k = 1; k < NCLS; k++) { float x = yp[k]; if (x > bs) { bs = x; bi = k; } }
                bool valid = (bi != 0) && (bs > 0.01f);
                uint hi = valid ? key_hi(bs) : __float_as_uint(NEGV);
                ull kk2 = ((ull)hi << 32) | ((uint)(e << 16)) | (uint)bi;
                if (kk2 >= nextk && kk2 < best) best = kk2;
            }
            #pragma unroll
            for (int off = 32; off; off >>= 1) {
                ull oo = __shfl_xor(best, off);
                if (oo < best) best = oo;
            }
            if (best >> 63) break;
            uint bhi = (uint)(best >> 32);
            uint idx = (uint)((best >> 16) & 0x7FFFull);
            float4 a = ((const float4*)box_tensor)[idx];
            const float* yp = y_pred + ((size_t)img * NBOX + idx) * 25;
            float4 cb = decode_box(yp[21], yp[22], yp[23], yp[24], a);
            float ca2 = area_of(cb);
            bool sup2 = false;
            #pragma unroll
            for (int t = 0; t < 2; t++) {
                int slot = lane + 64 * t;
                if (slot < A && sup_check(accbox[slot], accarea[slot], cb, ca2)) sup2 = true;
            }
            if (__ballot(sup2) == 0ull) {
                if (lane == 0) {
                    accbox[A] = cb; accarea[A] = ca2;
                    float* o = orow + A * 6;
                    o[0] = (float)((uint)best & 0x1Fu); o[1] = key_score(bhi);
                    o[2] = cb.x; o[3] = cb.y; o[4] = cb.z; o[5] = cb.w;
                }
                A++;
            }
            nextk = best + 1;
            __builtin_amdgcn_wave_barrier();
        }
    }

    for (int r = lane; r < (100 - A) * 6; r += 64) orow[A * 6 + r] = 0.f;
}

extern "C" void kernel_launch(void* const* d_in, const int* in_sizes, int n_in,
                              void* d_out, int out_size, void* d_ws, size_t ws_size,
                              hipStream_t stream)
{
    const float* y_pred     = (const float*)d_in[0];
    const float* box_tensor = (const float*)d_in[1];
    float* out = (float*)d_out;

    ull* K2 = (ull*)d_ws;                                        // 0.27 MB staged keys
    float4* SBX = (float4*)(K2 + (size_t)BATCH * NSEG * OUTW);   // 0.52 MB staged boxes

    decode_sort_kernel<<<dim3(NSEG, BATCH), 512, 0, stream>>>(y_pred, box_tensor, K2, SBX);
    nms_kernel<<<BATCH, 512, 0, stream>>>(K2, SBX, y_pred, box_tensor, out);
}